// Round 7
// baseline (85.729 us; speedup 1.0000x reference)
//
#include <hip/hip_runtime.h>
#include <hip/hip_bf16.h>
#include <math.h>

// Chamfer distance via MFMA, fp16 quantized / fp32 accumulate.
// K-packing: A_row = (-2ax,-2ay,-2az, 1, sqa, 0,0,0), B_col = (bx,by,bz, sqb, 1, ...)
// => MFMA dot = sqa + sqb - 2 a.b = full squared distance (from quantized coords).
// R7 vs R6: remove the (256,4) VGPR cap AND the unroll-4 pragma (R6 likely
// spilled: 8 MFMAs x 16 result regs vs 128-reg cap). Pressure kept low by
// construction: 2 tiles/iter (32 result regs), persistent B-operand quads with
// constant upper halves written once (no per-iter packing movs). reduce2 fused
// into reduce1 via atomicAdd (sweep zeroes out[0]; stream order protects it).

typedef _Float16 half8    __attribute__((ext_vector_type(8)));
typedef float    floatx16 __attribute__((ext_vector_type(16)));

constexpr int CH   = 2048;     // B points per block chunk
constexpr int ROWS = 128;      // 4 waves * 32 rows
constexpr int BLK  = 256;

__global__ __launch_bounds__(BLK) void chamfer_sweep_kernel(
    const float* __restrict__ P1, const float* __restrict__ P2,
    float* __restrict__ part, float* __restrict__ out,
    int n1, int n2, int YC)
{
    __shared__ uint2 sB[CH];          // per point: f16x4 (x, y, z, sqb)
    __shared__ float sRowMin[ROWS];

    const int dir  = blockIdx.z;
    const float* A = dir == 0 ? P1 : P2;
    const float* B = dir == 0 ? P2 : P1;
    const int nA   = dir == 0 ? n1 : n2;
    const int nB   = dir == 0 ? n2 : n1;
    float* pbase   = part + (dir == 0 ? 0 : (size_t)YC * n1);

    const int tid  = threadIdx.x;
    const int wave = tid >> 6;
    const int lane = tid & 63;
    const int n    = lane & 31;
    const int g    = lane >> 5;
    const bool g0  = (g == 0);

    if (blockIdx.x == 0 && blockIdx.y == 0 && blockIdx.z == 0 && tid == 0)
        out[0] = 0.0f;   // zeroed before reduce1 runs (stream order)

    // ---- stage B chunk: f16-quantized coords + sqb (from quantized coords) ----
    const int bstart = blockIdx.y * CH;
    for (int i = tid; i < CH; i += BLK) {
        int j = bstart + i; if (j >= nB) j = nB - 1;   // dup last point: min-safe
        float bx = B[3*j], by = B[3*j+1], bz = B[3*j+2];
        _Float16 hx = (_Float16)bx, hy = (_Float16)by, hz = (_Float16)bz;
        float qx = (float)hx, qy = (float)hy, qz = (float)hz;
        _Float16 hw = (_Float16)(qx*qx + qy*qy + qz*qz);
        union { _Float16 h[4]; uint2 u; } p;
        p.h[0] = hx; p.h[1] = hy; p.h[2] = hz; p.h[3] = hw;
        sB[i] = p.u;
    }

    // ---- A fragment: ONE 32-row tile per wave; zeros in k>=5 and all of g1 ----
    const _Float16 h0 = (_Float16)0.0f;
    half8 af;
    {
        int row = blockIdx.x * ROWS + wave * 32 + n;
        if (row >= nA) row = nA - 1;
        float ax = A[3*row], ay = A[3*row+1], az = A[3*row+2];
        _Float16 hax = (_Float16)ax, hay = (_Float16)ay, haz = (_Float16)az;
        float qx = (float)hax, qy = (float)hay, qz = (float)haz;
        _Float16 hs = (_Float16)(qx*qx + qy*qy + qz*qz);
        af[0] = g0 ? (_Float16)(-2.0f * qx) : h0;
        af[1] = g0 ? (_Float16)(-2.0f * qy) : h0;
        af[2] = g0 ? (_Float16)(-2.0f * qz) : h0;
        af[3] = g0 ? (_Float16)1.0f : h0;
        af[4] = g0 ? hs : h0;
        af[5] = h0; af[6] = h0; af[7] = h0;
    }

    __syncthreads();

    floatx16 rowmin;
#pragma unroll
    for (int r = 0; r < 16; ++r) rowmin[r] = 1e30f;
    const floatx16 zacc = {};

    // Persistent B-operand quads: upper pair (1.0h,0 | 0,0) written ONCE;
    // the per-iter ds_read_b64 lands directly in the lower pair.
    union BF { half8 v; unsigned u[4]; uint2 lo2[2]; };
    BF bu0, bu1;
    { union { _Float16 h[2]; unsigned u; } q;
      q.h[0] = (_Float16)1.0f; q.h[1] = h0;
      bu0.u[2] = q.u; bu0.u[3] = 0u;
      bu1.u[2] = q.u; bu1.u[3] = 0u; }

    // ---- main sweep: 2 B col-tiles (64 points) per iteration, 2 MFMAs ----
    for (int bt = 0; bt < CH / 64; ++bt) {
        bu0.lo2[0] = sB[bt * 64 + n];        // broadcast: g0/g1 read same addr
        bu1.lo2[0] = sB[bt * 64 + 32 + n];

        floatx16 d0 = __builtin_amdgcn_mfma_f32_32x32x16_f16(af, bu0.v, zacc, 0, 0, 0);
        floatx16 d1 = __builtin_amdgcn_mfma_f32_32x32x16_f16(af, bu1.v, zacc, 0, 0, 0);

#pragma unroll
        for (int r = 0; r < 16; ++r)
            rowmin[r] = fminf(fminf(rowmin[r], d0[r]), d1[r]);   // v_min3
    }

    // ---- epilogue: reduce across the 32 cols (xor-shuffle within n-group) ----
#pragma unroll
    for (int mask = 1; mask <= 16; mask <<= 1)
#pragma unroll
        for (int r = 0; r < 16; ++r)
            rowmin[r] = fminf(rowmin[r], __shfl_xor(rowmin[r], mask));

    if (n == 0) {
#pragma unroll
        for (int r = 0; r < 16; ++r) {
            int rr = wave * 32 + g * 4 + ((r & 3) + 8 * (r >> 2));   // C/D row map
            sRowMin[rr] = rowmin[r];
        }
    }
    __syncthreads();

    if (tid < ROWS) {   // one partial slot per (dir,row,ychunk) — no atomics
        int grow = blockIdx.x * ROWS + tid;
        if (grow < nA) pbase[(size_t)grow * YC + blockIdx.y] = sRowMin[tid];
    }
}

// Per-row min over YC contiguous partials -> sqrt -> block sum -> atomicAdd(out)
__global__ __launch_bounds__(256) void reduce_kernel(
    const float* __restrict__ part, float* __restrict__ out,
    int ntot, int YC)
{
    __shared__ float s[256];
    int r = blockIdx.x * 256 + threadIdx.x;
    float acc = 0.0f;
    if (r < ntot) {
        const float* p = part + (size_t)r * YC;
        float m = 1e30f;
        for (int y = 0; y < YC; ++y) m = fminf(m, p[y]);
        acc = sqrtf(fmaxf(m, 0.0f));
    }
    s[threadIdx.x] = acc;
    __syncthreads();
    for (int w = 128; w > 0; w >>= 1) {
        if (threadIdx.x < w) s[threadIdx.x] += s[threadIdx.x + w];
        __syncthreads();
    }
    if (threadIdx.x == 0) atomicAdd(out, s[0]);
}

extern "C" void kernel_launch(void* const* d_in, const int* in_sizes, int n_in,
                              void* d_out, int out_size, void* d_ws, size_t ws_size,
                              hipStream_t stream) {
    const float* P1 = (const float*)d_in[0];
    const float* P2 = (const float*)d_in[1];
    const int n1 = in_sizes[0] / 3;   // 16384
    const int n2 = in_sizes[1] / 3;   // 16384
    const int nmax = (n1 > n2) ? n1 : n2;
    const int YC = (nmax + CH - 1) / CH;          // y-chunks (same grid both dirs)

    float* part = (float*)d_ws;                   // [(n1+n2) * YC] partial row-mins
    float* out  = (float*)d_out;

    {   // two independent sweeps (z = direction), pure register row-mins
        dim3 grid((nmax + ROWS - 1) / ROWS, YC, 2);
        chamfer_sweep_kernel<<<grid, BLK, 0, stream>>>(P1, P2, part, out, n1, n2, YC);
    }
    int nb = (n1 + n2 + 255) / 256;
    reduce_kernel<<<nb, 256, 0, stream>>>(part, out, n1 + n2, YC);
}

// Round 8
// 79.837 us; speedup vs baseline: 1.0738x; 1.0738x over previous
//
#include <hip/hip_runtime.h>
#include <hip/hip_bf16.h>
#include <math.h>

// Chamfer distance via MFMA, fp16 quantized / fp32 accumulate.
// K-packing: A_row = (-2ax,-2ay,-2az, 1, sqa, 0,0,0), B_col = (bx,by,bz, sqb, 1, ...)
// => MFMA dot = sqa + sqb - 2 a.b = full squared distance (from quantized coords).
// R8 vs R6/R7: exactly FOUR independent 32x32x16 MFMA tiles per loop body
// (R7's 2 exposed MFMA+LDS latency; R6's unroll-4 -> 8 tiles blew the 128-reg
// cliff). Live set at the min3 point ~115 VGPRs -> 4 waves/EU, no spills;
// 4 waves x 4-deep pipeline = 16 MFMAs in flight per SIMD. 8 v_min3 per MFMA
// via chained min3. Same two-sweep / register-rowmin / no-atomic structure.

typedef _Float16 half8    __attribute__((ext_vector_type(8)));
typedef float    floatx16 __attribute__((ext_vector_type(16)));

constexpr int CH   = 2048;     // B points per block chunk
constexpr int ROWS = 128;      // 4 waves * 32 rows
constexpr int BLK  = 256;

__global__ __launch_bounds__(BLK, 4) void chamfer_sweep_kernel(
    const float* __restrict__ P1, const float* __restrict__ P2,
    float* __restrict__ part, float* __restrict__ out,
    int n1, int n2, int YC)
{
    __shared__ uint2 sB[CH];          // per point: f16x4 (x, y, z, sqb)
    __shared__ float sRowMin[ROWS];

    const int dir  = blockIdx.z;
    const float* A = dir == 0 ? P1 : P2;
    const float* B = dir == 0 ? P2 : P1;
    const int nA   = dir == 0 ? n1 : n2;
    const int nB   = dir == 0 ? n2 : n1;
    float* pbase   = part + (dir == 0 ? 0 : (size_t)YC * n1);

    const int tid  = threadIdx.x;
    const int wave = tid >> 6;
    const int lane = tid & 63;
    const int n    = lane & 31;
    const int g    = lane >> 5;
    const bool g0  = (g == 0);

    if (blockIdx.x == 0 && blockIdx.y == 0 && blockIdx.z == 0 && tid == 0)
        out[0] = 0.0f;   // zeroed before reduce runs (stream order)

    // ---- stage B chunk: f16-quantized coords + sqb (from quantized coords) ----
    const int bstart = blockIdx.y * CH;
    for (int i = tid; i < CH; i += BLK) {
        int j = bstart + i; if (j >= nB) j = nB - 1;   // dup last point: min-safe
        float bx = B[3*j], by = B[3*j+1], bz = B[3*j+2];
        _Float16 hx = (_Float16)bx, hy = (_Float16)by, hz = (_Float16)bz;
        float qx = (float)hx, qy = (float)hy, qz = (float)hz;
        _Float16 hw = (_Float16)(qx*qx + qy*qy + qz*qz);
        union { _Float16 h[4]; uint2 u; } p;
        p.h[0] = hx; p.h[1] = hy; p.h[2] = hz; p.h[3] = hw;
        sB[i] = p.u;
    }

    // ---- A fragment: ONE 32-row tile per wave; zeros in k>=5 and all of g1 ----
    const _Float16 h0 = (_Float16)0.0f;
    half8 af;
    {
        int row = blockIdx.x * ROWS + wave * 32 + n;
        if (row >= nA) row = nA - 1;
        float ax = A[3*row], ay = A[3*row+1], az = A[3*row+2];
        _Float16 hax = (_Float16)ax, hay = (_Float16)ay, haz = (_Float16)az;
        float qx = (float)hax, qy = (float)hay, qz = (float)haz;
        _Float16 hs = (_Float16)(qx*qx + qy*qy + qz*qz);
        af[0] = g0 ? (_Float16)(-2.0f * qx) : h0;
        af[1] = g0 ? (_Float16)(-2.0f * qy) : h0;
        af[2] = g0 ? (_Float16)(-2.0f * qz) : h0;
        af[3] = g0 ? (_Float16)1.0f : h0;
        af[4] = g0 ? hs : h0;
        af[5] = h0; af[6] = h0; af[7] = h0;
    }

    __syncthreads();

    floatx16 rowmin;
#pragma unroll
    for (int r = 0; r < 16; ++r) rowmin[r] = 1e30f;
    const floatx16 zacc = {};

    // Persistent B-operand quads: upper pair (1.0h,0 | 0,0) written ONCE;
    // per-iter ds_read_b64 lands directly in the lower pair.
    union BF { half8 v; unsigned u[4]; uint2 lo; };
    BF bu0, bu1, bu2, bu3;
    { union { _Float16 h[2]; unsigned u; } q;
      q.h[0] = (_Float16)1.0f; q.h[1] = h0;
      bu0.u[2] = q.u; bu0.u[3] = 0u;
      bu1.u[2] = q.u; bu1.u[3] = 0u;
      bu2.u[2] = q.u; bu2.u[3] = 0u;
      bu3.u[2] = q.u; bu3.u[3] = 0u; }

    // ---- main sweep: 4 B col-tiles (128 points) per iteration, 4 MFMAs ----
    for (int bt = 0; bt < CH / 128; ++bt) {
        const uint2* p = sB + bt * 128 + n;    // broadcast: g0/g1 read same addr
        bu0.lo = p[0];
        bu1.lo = p[32];
        bu2.lo = p[64];
        bu3.lo = p[96];

        floatx16 d0 = __builtin_amdgcn_mfma_f32_32x32x16_f16(af, bu0.v, zacc, 0, 0, 0);
        floatx16 d1 = __builtin_amdgcn_mfma_f32_32x32x16_f16(af, bu1.v, zacc, 0, 0, 0);
        floatx16 d2 = __builtin_amdgcn_mfma_f32_32x32x16_f16(af, bu2.v, zacc, 0, 0, 0);
        floatx16 d3 = __builtin_amdgcn_mfma_f32_32x32x16_f16(af, bu3.v, zacc, 0, 0, 0);

#pragma unroll
        for (int r = 0; r < 16; ++r) {
            float t = fminf(fminf(rowmin[r], d0[r]), d1[r]);     // v_min3
            rowmin[r] = fminf(fminf(t, d2[r]), d3[r]);           // v_min3
        }
    }

    // ---- epilogue: reduce across the 32 cols (xor-shuffle within n-group) ----
#pragma unroll
    for (int mask = 1; mask <= 16; mask <<= 1)
#pragma unroll
        for (int r = 0; r < 16; ++r)
            rowmin[r] = fminf(rowmin[r], __shfl_xor(rowmin[r], mask));

    if (n == 0) {
#pragma unroll
        for (int r = 0; r < 16; ++r) {
            int rr = wave * 32 + g * 4 + ((r & 3) + 8 * (r >> 2));   // C/D row map
            sRowMin[rr] = rowmin[r];
        }
    }
    __syncthreads();

    if (tid < ROWS) {   // one partial slot per (dir,row,ychunk) — no atomics
        int grow = blockIdx.x * ROWS + tid;
        if (grow < nA) pbase[(size_t)grow * YC + blockIdx.y] = sRowMin[tid];
    }
}

// Per-row min over YC contiguous partials -> sqrt -> block sum -> atomicAdd(out)
__global__ __launch_bounds__(256) void reduce_kernel(
    const float* __restrict__ part, float* __restrict__ out,
    int ntot, int YC)
{
    __shared__ float s[256];
    int r = blockIdx.x * 256 + threadIdx.x;
    float acc = 0.0f;
    if (r < ntot) {
        const float* p = part + (size_t)r * YC;
        float m = 1e30f;
        for (int y = 0; y < YC; ++y) m = fminf(m, p[y]);
        acc = sqrtf(fmaxf(m, 0.0f));
    }
    s[threadIdx.x] = acc;
    __syncthreads();
    for (int w = 128; w > 0; w >>= 1) {
        if (threadIdx.x < w) s[threadIdx.x] += s[threadIdx.x + w];
        __syncthreads();
    }
    if (threadIdx.x == 0) atomicAdd(out, s[0]);
}

extern "C" void kernel_launch(void* const* d_in, const int* in_sizes, int n_in,
                              void* d_out, int out_size, void* d_ws, size_t ws_size,
                              hipStream_t stream) {
    const float* P1 = (const float*)d_in[0];
    const float* P2 = (const float*)d_in[1];
    const int n1 = in_sizes[0] / 3;   // 16384
    const int n2 = in_sizes[1] / 3;   // 16384
    const int nmax = (n1 > n2) ? n1 : n2;
    const int YC = (nmax + CH - 1) / CH;          // y-chunks (same grid both dirs)

    float* part = (float*)d_ws;                   // [(n1+n2) * YC] partial row-mins
    float* out  = (float*)d_out;

    {   // two independent sweeps (z = direction), pure register row-mins
        dim3 grid((nmax + ROWS - 1) / ROWS, YC, 2);
        chamfer_sweep_kernel<<<grid, BLK, 0, stream>>>(P1, P2, part, out, n1, n2, YC);
    }
    int nb = (n1 + n2 + 255) / 256;
    reduce_kernel<<<nb, 256, 0, stream>>>(part, out, n1 + n2, YC);
}

// Round 9
// 77.403 us; speedup vs baseline: 1.1076x; 1.0314x over previous
//
#include <hip/hip_runtime.h>
#include <hip/hip_bf16.h>
#include <math.h>

// Chamfer distance via MFMA, fp16 quantized / fp32 accumulate.
// K-packing: A_row = (-2ax,-2ay,-2az, 1, sqa, 0,0,0), B_col = (bx,by,bz, sqb, 1, ...)
// => MFMA dot = sqa + sqb - 2 a.b = full squared distance (from quantized coords).
// R9 vs R8: quantization hoisted into a one-shot PACK kernel (points -> uint2
// f16 fragments in d_ws). Sweep staging becomes a raw 32KB copy (no math, no
// scattered loads); CH 4096 (32KB LDS) -> grid 1024 blocks = exactly 4/CU,
// ONE residency round, 32-iter loop. Keeps R8's 4-deep MFMA pipeline + min3
// body and (256,4) bound (~112 live VGPRs).

typedef _Float16 half8    __attribute__((ext_vector_type(8)));
typedef float    floatx16 __attribute__((ext_vector_type(16)));

constexpr int CH   = 4096;     // B points per block chunk (32 KB LDS)
constexpr int ROWS = 128;      // 4 waves * 32 rows
constexpr int BLK  = 256;

// ---- pack both clouds into f16 fragments (x,y,z,|p|^2), padded to NP ----
__global__ __launch_bounds__(256) void pack_kernel(
    const float* __restrict__ P1, const float* __restrict__ P2,
    uint2* __restrict__ F1, uint2* __restrict__ F2,
    int n1, int n2, int NP, float* __restrict__ out)
{
    int i = blockIdx.x * 256 + threadIdx.x;
    if (i == 0) out[0] = 0.0f;           // zeroed before reduce runs (stream order)
    const float* P; uint2* F; int n, idx;
    if (i < NP)          { P = P1; F = F1; n = n1; idx = i; }
    else if (i < 2 * NP) { P = P2; F = F2; n = n2; idx = i - NP; }
    else return;
    int j = idx < n ? idx : n - 1;       // pad with dup of last point: min-safe
    float x = P[3*j], y = P[3*j+1], z = P[3*j+2];
    _Float16 hx = (_Float16)x, hy = (_Float16)y, hz = (_Float16)z;
    float qx = (float)hx, qy = (float)hy, qz = (float)hz;
    _Float16 hw = (_Float16)(qx*qx + qy*qy + qz*qz);
    union { _Float16 h[4]; uint2 u; } p;
    p.h[0] = hx; p.h[1] = hy; p.h[2] = hz; p.h[3] = hw;
    F[idx] = p.u;
}

__global__ __launch_bounds__(BLK, 4) void chamfer_sweep_kernel(
    const uint2* __restrict__ F1, const uint2* __restrict__ F2,
    float* __restrict__ part, int n1, int n2, int YC)
{
    __shared__ uint2 sB[CH];          // pre-packed fragments, straight copy
    __shared__ float sRowMin[ROWS];

    const int dir   = blockIdx.z;
    const uint2* FA = dir == 0 ? F1 : F2;
    const uint2* FB = dir == 0 ? F2 : F1;
    const int nA    = dir == 0 ? n1 : n2;
    float* pbase    = part + (dir == 0 ? 0 : (size_t)YC * n1);

    const int tid  = threadIdx.x;
    const int wave = tid >> 6;
    const int lane = tid & 63;
    const int n    = lane & 31;
    const int g    = lane >> 5;
    const bool g0  = (g == 0);

    // ---- stage: pure 32KB copy, 16B granules (no math, coalesced) ----
    {
        const uint4* src = (const uint4*)(FB + (size_t)blockIdx.y * CH);
        uint4* dst = (uint4*)sB;
        for (int i = tid; i < CH / 2; i += BLK) dst[i] = src[i];
    }

    // ---- A fragment: one 8B load + 3 f16 muls (exact *-2) ----
    const _Float16 h0 = (_Float16)0.0f;
    half8 af;
    {
        int arow = blockIdx.x * ROWS + wave * 32 + n;   // < NP by construction
        union { uint2 u; _Float16 h[4]; } au; au.u = FA[arow];
        const _Float16 m2 = (_Float16)(-2.0f);
        af[0] = g0 ? (_Float16)(au.h[0] * m2) : h0;
        af[1] = g0 ? (_Float16)(au.h[1] * m2) : h0;
        af[2] = g0 ? (_Float16)(au.h[2] * m2) : h0;
        af[3] = g0 ? (_Float16)1.0f : h0;
        af[4] = g0 ? au.h[3] : h0;
        af[5] = h0; af[6] = h0; af[7] = h0;
    }

    __syncthreads();

    floatx16 rowmin;
#pragma unroll
    for (int r = 0; r < 16; ++r) rowmin[r] = 1e30f;
    const floatx16 zacc = {};

    // Persistent B-operand quads: upper pair (1.0h,0 | 0,0) written ONCE;
    // per-iter ds_read_b64 lands directly in the lower pair.
    union BF { half8 v; unsigned u[4]; uint2 lo; };
    BF bu0, bu1, bu2, bu3;
    { union { _Float16 h[2]; unsigned u; } q;
      q.h[0] = (_Float16)1.0f; q.h[1] = h0;
      bu0.u[2] = q.u; bu0.u[3] = 0u;
      bu1.u[2] = q.u; bu1.u[3] = 0u;
      bu2.u[2] = q.u; bu2.u[3] = 0u;
      bu3.u[2] = q.u; bu3.u[3] = 0u; }

    // ---- main sweep: 4 B col-tiles (128 points) per iteration, 4 MFMAs ----
    for (int bt = 0; bt < CH / 128; ++bt) {
        const uint2* p = sB + bt * 128 + n;    // broadcast: g0/g1 read same addr
        bu0.lo = p[0];
        bu1.lo = p[32];
        bu2.lo = p[64];
        bu3.lo = p[96];

        floatx16 d0 = __builtin_amdgcn_mfma_f32_32x32x16_f16(af, bu0.v, zacc, 0, 0, 0);
        floatx16 d1 = __builtin_amdgcn_mfma_f32_32x32x16_f16(af, bu1.v, zacc, 0, 0, 0);
        floatx16 d2 = __builtin_amdgcn_mfma_f32_32x32x16_f16(af, bu2.v, zacc, 0, 0, 0);
        floatx16 d3 = __builtin_amdgcn_mfma_f32_32x32x16_f16(af, bu3.v, zacc, 0, 0, 0);

#pragma unroll
        for (int r = 0; r < 16; ++r) {
            float t = fminf(fminf(rowmin[r], d0[r]), d1[r]);     // v_min3
            rowmin[r] = fminf(fminf(t, d2[r]), d3[r]);           // v_min3
        }
    }

    // ---- epilogue: reduce across the 32 cols (xor-shuffle within n-group) ----
#pragma unroll
    for (int mask = 1; mask <= 16; mask <<= 1)
#pragma unroll
        for (int r = 0; r < 16; ++r)
            rowmin[r] = fminf(rowmin[r], __shfl_xor(rowmin[r], mask));

    if (n == 0) {
#pragma unroll
        for (int r = 0; r < 16; ++r) {
            int rr = wave * 32 + g * 4 + ((r & 3) + 8 * (r >> 2));   // C/D row map
            sRowMin[rr] = rowmin[r];
        }
    }
    __syncthreads();

    if (tid < ROWS) {   // one partial slot per (dir,row,ychunk) — no atomics
        int grow = blockIdx.x * ROWS + tid;
        if (grow < nA) pbase[(size_t)grow * YC + blockIdx.y] = sRowMin[tid];
    }
}

// Per-row min over YC contiguous partials -> sqrt -> block sum -> atomicAdd(out)
__global__ __launch_bounds__(256) void reduce_kernel(
    const float* __restrict__ part, float* __restrict__ out,
    int ntot, int YC)
{
    __shared__ float s[256];
    int r = blockIdx.x * 256 + threadIdx.x;
    float acc = 0.0f;
    if (r < ntot) {
        float m;
        if (YC == 4) {   // fast path: one 16B load (part is 16B-aligned, r*4 floats)
            const float4 v = ((const float4*)part)[r];
            m = fminf(fminf(v.x, v.y), fminf(v.z, v.w));
        } else {
            const float* p = part + (size_t)r * YC;
            m = 1e30f;
            for (int y = 0; y < YC; ++y) m = fminf(m, p[y]);
        }
        acc = sqrtf(fmaxf(m, 0.0f));
    }
    s[threadIdx.x] = acc;
    __syncthreads();
    for (int w = 128; w > 0; w >>= 1) {
        if (threadIdx.x < w) s[threadIdx.x] += s[threadIdx.x + w];
        __syncthreads();
    }
    if (threadIdx.x == 0) atomicAdd(out, s[0]);
}

extern "C" void kernel_launch(void* const* d_in, const int* in_sizes, int n_in,
                              void* d_out, int out_size, void* d_ws, size_t ws_size,
                              hipStream_t stream) {
    const float* P1 = (const float*)d_in[0];
    const float* P2 = (const float*)d_in[1];
    const int n1 = in_sizes[0] / 3;   // 16384
    const int n2 = in_sizes[1] / 3;   // 16384
    const int nmax = (n1 > n2) ? n1 : n2;
    const int YC = (nmax + CH - 1) / CH;          // y-chunks (4)
    const int NP = YC * CH;                       // padded point count (16384)

    uint2* F1   = (uint2*)d_ws;                   // packed fragments, cloud 1
    uint2* F2   = F1 + NP;                        // packed fragments, cloud 2
    float* part = (float*)(F2 + NP);              // [(n1+n2) * YC] partial row-mins
    float* out  = (float*)d_out;

    pack_kernel<<<(2 * NP + 255) / 256, 256, 0, stream>>>(P1, P2, F1, F2, n1, n2, NP, out);

    {   // two independent sweeps (z = direction), pure register row-mins
        dim3 grid(NP / ROWS, YC, 2);
        chamfer_sweep_kernel<<<grid, BLK, 0, stream>>>(F1, F2, part, n1, n2, YC);
    }
    reduce_kernel<<<(n1 + n2 + 255) / 256, 256, 0, stream>>>(part, out, n1 + n2, YC);
}